// Round 1
// baseline (372.531 us; speedup 1.0000x reference)
//
#include <hip/hip_runtime.h>

// SortPooling: B=8192 graphs, spans of n in [32,96] rows over features
// (n_total x 128 fp32). Select top-K=30 rows per graph by last column
// (descending, stable ties by lower index), write full rows to out.
//
// One 256-thread block per graph:
//   phase 1: stage keys (strided col-127 reads) into LDS
//   phase 2: O(n^2) stable rank; rank<K scatters index into sel[rank]
//   phase 3: cooperative float4 copy of the K selected rows

#define KSEL   30
#define MAXN   96
#define DIM    128
#define BLOCK  256

__global__ __launch_bounds__(BLOCK) void sortpool_kernel(
    const float* __restrict__ feat,
    const int*   __restrict__ gi,
    float*       __restrict__ out)
{
    const int b = blockIdx.x;
    const int t = threadIdx.x;

    __shared__ float key[MAXN];
    __shared__ int   sel[KSEL];

    const int start = gi[2 * b];
    const int end   = gi[2 * b + 1];
    int n = end - start;
    if (n > MAXN) n = MAXN;

    if (t < KSEL) sel[t] = -1;          // guard: only matters if n < K (never here)
    if (t < n)
        key[t] = feat[(size_t)(start + t) * DIM + (DIM - 1)];
    __syncthreads();

    if (t < n) {
        const float ki = key[t];
        int rank = 0;
        #pragma unroll 4
        for (int j = 0; j < n; ++j) {
            const float kj = key[j];
            // stable descending rank: strictly greater, or equal with lower index
            rank += (kj > ki) || (kj == ki && j < t);
        }
        if (rank < KSEL) sel[rank] = t;
    }
    __syncthreads();

    // K*DIM/4 = 30*32 = 960 float4s per graph; 256 threads -> <=4 each.
    const size_t out_base = (size_t)b * (KSEL * DIM);
    for (int e = t; e < KSEL * (DIM / 4); e += BLOCK) {
        const int k = e >> 5;           // which of the K rows (32 float4 per row)
        const int c = (e & 31) << 2;    // float offset within row
        const int r = sel[k];
        float4 v;
        if (r >= 0) {
            v = *(const float4*)&feat[(size_t)(start + r) * DIM + c];
        } else {
            v = make_float4(0.f, 0.f, 0.f, 0.f);
        }
        *(float4*)&out[out_base + (size_t)k * DIM + c] = v;
    }
}

extern "C" void kernel_launch(void* const* d_in, const int* in_sizes, int n_in,
                              void* d_out, int out_size, void* d_ws, size_t ws_size,
                              hipStream_t stream) {
    const float* feat = (const float*)d_in[0];
    const int*   gi   = (const int*)d_in[1];   // graph_indexes as int32 (x64 off)
    float*       out  = (float*)d_out;

    const int B = in_sizes[1] / 2;             // 8192 graphs
    sortpool_kernel<<<dim3(B), dim3(BLOCK), 0, stream>>>(feat, gi, out);
}